// Round 1
// baseline (772.829 us; speedup 1.0000x reference)
//
#include <hip/hip_runtime.h>
#include <math.h>

static constexpr int Bn = 2, Tn = 2048, Dn = 768, Hn = 8, Kn = 64, Vn = 96;

// ---------------- f0 threshold table ----------------
// f0(a) = #{ i in [0,16) : cw[i] <= a },  cw[i] = pow_rate^(i+1) - 1,
// pow_rate = (T+1)^(1/16). Boundaries are >=0.088 away from integers, so
// double-precision recurrence matches JAX's f32 compute exactly on integers.
__global__ void f0_kernel(int* __restrict__ f0_tab) {
    int a = blockIdx.x * blockDim.x + threadIdx.x;
    if (a >= Tn) return;
    double pr = exp(log((double)(Tn + 1)) / 16.0);
    double w = 1.0; int cnt = 0;
    for (int i = 0; i < 16; ++i) { w *= pr; if ((w - 1.0) <= (double)a) cnt++; }
    f0_tab[a] = cnt;
}

// ---------------- fused QKV projection ----------------
// X[4096,768] @ [Wq|Wk|Wv] -> qh(scaled)/kh [B,H,T,64], vh [B,H,T,96]
__global__ __launch_bounds__(256) void proj_kernel(
    const float* __restrict__ X, const float* __restrict__ Wq,
    const float* __restrict__ Wk, const float* __restrict__ Wv,
    float* __restrict__ qh, float* __restrict__ kh, float* __restrict__ vh) {
    __shared__ __attribute__((aligned(16))) float As[16][68];
    __shared__ __attribute__((aligned(16))) float Bs[16][68];
    const int tid = threadIdx.x;
    const int tx = tid & 15, ty = tid >> 4;
    const int rowBase = blockIdx.y * 64;
    const int colBase = blockIdx.x * 64;
    const float* Wsrc; int ldw, cb0;
    if (colBase < 512)       { Wsrc = Wq; ldw = 512; cb0 = colBase; }
    else if (colBase < 1024) { Wsrc = Wk; ldw = 512; cb0 = colBase - 512; }
    else                     { Wsrc = Wv; ldw = 768; cb0 = colBase - 1024; }
    const int lrow = tid >> 2, lc4 = (tid & 3) << 2;
    const int brow = tid >> 4, bc4 = (tid & 15) << 2;
    float acc[4][4] = {};
    for (int k0 = 0; k0 < Dn; k0 += 16) {
        const float4 av = *(const float4*)&X[(size_t)(rowBase + lrow) * Dn + k0 + lc4];
        const float4 bv = *(const float4*)&Wsrc[(size_t)(k0 + brow) * ldw + cb0 + bc4];
        __syncthreads();
        As[lc4 + 0][lrow] = av.x; As[lc4 + 1][lrow] = av.y;
        As[lc4 + 2][lrow] = av.z; As[lc4 + 3][lrow] = av.w;
        *(float4*)&Bs[brow][bc4] = bv;
        __syncthreads();
#pragma unroll
        for (int kk = 0; kk < 16; ++kk) {
            const float4 a4 = *(const float4*)&As[kk][ty << 2];
            const float4 b4 = *(const float4*)&Bs[kk][tx << 2];
            const float aa[4] = {a4.x, a4.y, a4.z, a4.w};
            const float bb[4] = {b4.x, b4.y, b4.z, b4.w};
#pragma unroll
            for (int i = 0; i < 4; ++i)
#pragma unroll
                for (int j = 0; j < 4; ++j) acc[i][j] += aa[i] * bb[j];
        }
    }
#pragma unroll
    for (int i = 0; i < 4; ++i) {
        const int n = rowBase + ty * 4 + i;
        const int b = n >> 11, t = n & (Tn - 1);
#pragma unroll
        for (int j = 0; j < 4; ++j) {
            const int gc = colBase + tx * 4 + j;
            const float v = acc[i][j];
            if (gc < 512) {
                qh[(((size_t)b * Hn + (gc >> 6)) * Tn + t) * Kn + (gc & 63)] = v * 0.125f;
            } else if (gc < 1024) {
                const int c2 = gc - 512;
                kh[(((size_t)b * Hn + (c2 >> 6)) * Tn + t) * Kn + (c2 & 63)] = v;
            } else {
                const int c3 = gc - 1024;
                vh[(((size_t)b * Hn + (c3 / 96)) * Tn + t) * Vn + (c3 % 96)] = v;
            }
        }
    }
}

// ---------------- rel-bias suffix sums S1/S2 and content bias cb ----------------
__global__ __launch_bounds__(256) void bias_kernel(
    const float* __restrict__ qh, const float* __restrict__ kh,
    const float* __restrict__ Wrk, const float* __restrict__ rwb,
    const float* __restrict__ rrb, float* __restrict__ S, float* __restrict__ cbuf) {
    __shared__ __attribute__((aligned(16))) float qs[32][68];
    __shared__ __attribute__((aligned(16))) float ks[32][68];
    __shared__ __attribute__((aligned(16))) float wr[32][68];
    __shared__ __attribute__((aligned(16))) float rr[64];
    __shared__ __attribute__((aligned(16))) float rw[64];
    __shared__ float us[32][36];
    const int tid = threadIdx.x;
    const int bh = blockIdx.y, h = bh & 7;
    const int t0 = blockIdx.x * 32;
    const int row = tid >> 3, g = tid & 7;
    {
        const float* qr = qh + ((size_t)bh * Tn + t0 + row) * Kn + g * 8;
        const float* kr = kh + ((size_t)bh * Tn + t0 + row) * Kn + g * 8;
        *(float4*)&qs[row][g * 8]     = *(const float4*)qr;
        *(float4*)&qs[row][g * 8 + 4] = *(const float4*)(qr + 4);
        *(float4*)&ks[row][g * 8]     = *(const float4*)kr;
        *(float4*)&ks[row][g * 8 + 4] = *(const float4*)(kr + 4);
        const float* wrp = Wrk + (size_t)row * (Hn * Kn) + h * Kn + g * 8;
        *(float4*)&wr[row][g * 8]     = *(const float4*)wrp;
        *(float4*)&wr[row][g * 8 + 4] = *(const float4*)(wrp + 4);
    }
    if (tid < 64) { rr[tid] = rrb[h * Kn + tid]; rw[tid] = rwb[h * Kn + tid]; }
    __syncthreads();
#pragma unroll
    for (int ii = 0; ii < 4; ++ii) {
        const int i = g * 4 + ii;
        float acc = 0.f;
#pragma unroll
        for (int kk = 0; kk < 64; kk += 4) {
            const float4 q4 = *(const float4*)&qs[row][kk];
            const float4 r4 = *(const float4*)&rr[kk];
            const float4 w4 = *(const float4*)&wr[i][kk];
            acc += (q4.x + r4.x) * w4.x + (q4.y + r4.y) * w4.y +
                   (q4.z + r4.z) * w4.z + (q4.w + r4.w) * w4.w;
        }
        us[row][i] = acc;
    }
    float c = 0.f;
#pragma unroll
    for (int j = 0; j < 8; ++j) c += rw[g * 8 + j] * ks[row][g * 8 + j];
    c += __shfl_xor(c, 1, 8); c += __shfl_xor(c, 2, 8); c += __shfl_xor(c, 4, 8);
    if (g == 0) cbuf[(size_t)bh * Tn + t0 + row] = c;
    __syncthreads();
    if (g < 2) {
        float s = 0.f;
        float* dst = S + ((size_t)bh * Tn + t0 + row) * 34 + (g == 0 ? 0 : 17);
        const int base = (g == 0) ? 0 : 16;
        dst[16] = 0.f;
        for (int i = 15; i >= 0; --i) { s += us[row][base + i]; dst[i] = s; }
    }
}

// ---------------- flash attention with rel-position bias ----------------
// block: 32 q-rows, 256 threads (tx,ty)=(16,16); thread owns logits
// (t in {ty,ty+16}) x (s in {tx,tx+16}) and acc rows {ty,ty+16} x v-cols tx*6..+5
__global__ __launch_bounds__(256) void attn_kernel(
    const float* __restrict__ qh, const float* __restrict__ kh,
    const float* __restrict__ vh, const float* __restrict__ S,
    const float* __restrict__ cbuf, const int* __restrict__ f0_tab,
    float* __restrict__ P) {
    __shared__ __attribute__((aligned(16))) float qs[32][68];
    __shared__ __attribute__((aligned(16))) float ks[32][68];
    __shared__ __attribute__((aligned(16))) float vs[32][100];
    __shared__ __attribute__((aligned(16))) float ps[32][36];
    __shared__ float Ss[32][34];
    __shared__ float cbs[32];
    __shared__ unsigned char f0s[Tn];
    const int tid = threadIdx.x;
    const int tx = tid & 15, ty = tid >> 4;
    const int bh = blockIdx.y, b = bh >> 3, h = bh & 7;
    const int t0 = blockIdx.x * 32;
    const int lrow = tid >> 3, g8 = (tid & 7) * 8, g12 = (tid & 7) * 12;
    {
        const float* qr = qh + ((size_t)bh * Tn + t0 + lrow) * Kn + g8;
        *(float4*)&qs[lrow][g8]     = *(const float4*)qr;
        *(float4*)&qs[lrow][g8 + 4] = *(const float4*)(qr + 4);
    }
    for (int idx = tid; idx < 32 * 34; idx += 256)
        Ss[idx / 34][idx % 34] = S[((size_t)bh * Tn + t0 + idx / 34) * 34 + idx % 34];
    for (int idx = tid; idx < Tn; idx += 256) f0s[idx] = (unsigned char)f0_tab[idx];
    float m0 = -INFINITY, m1 = -INFINITY, l0 = 0.f, l1 = 0.f;
    float a0[6] = {}, a1[6] = {};
    const int tg0 = t0 + ty, tg1 = t0 + ty + 16;
    for (int s0 = 0; s0 < Tn; s0 += 32) {
        const float* kr = kh + ((size_t)bh * Tn + s0 + lrow) * Kn + g8;
        const float4 kv0 = *(const float4*)kr;
        const float4 kv1 = *(const float4*)(kr + 4);
        const float* vr = vh + ((size_t)bh * Tn + s0 + lrow) * Vn + g12;
        const float4 vv0 = *(const float4*)vr;
        const float4 vv1 = *(const float4*)(vr + 4);
        const float4 vv2 = *(const float4*)(vr + 8);
        float cbv = 0.f;
        if (tid < 32) cbv = cbuf[(size_t)bh * Tn + s0 + tid];
        __syncthreads();   // prev tile's PV reads done before overwrite
        *(float4*)&ks[lrow][g8]      = kv0;
        *(float4*)&ks[lrow][g8 + 4]  = kv1;
        *(float4*)&vs[lrow][g12]     = vv0;
        *(float4*)&vs[lrow][g12 + 4] = vv1;
        *(float4*)&vs[lrow][g12 + 8] = vv2;
        if (tid < 32) cbs[tid] = cbv;
        __syncthreads();
        float d00 = 0.f, d01 = 0.f, d10 = 0.f, d11 = 0.f;
#pragma unroll
        for (int kk = 0; kk < 64; kk += 4) {
            const float4 qa = *(const float4*)&qs[ty][kk];
            const float4 qb = *(const float4*)&qs[ty + 16][kk];
            const float4 ka = *(const float4*)&ks[tx][kk];
            const float4 kb = *(const float4*)&ks[tx + 16][kk];
            d00 += qa.x * ka.x + qa.y * ka.y + qa.z * ka.z + qa.w * ka.w;
            d01 += qa.x * kb.x + qa.y * kb.y + qa.z * kb.z + qa.w * kb.w;
            d10 += qb.x * ka.x + qb.y * ka.y + qb.z * ka.z + qb.w * ka.w;
            d11 += qb.x * kb.x + qb.y * kb.y + qb.z * kb.z + qb.w * kb.w;
        }
        const int sg0 = s0 + tx, sg1 = s0 + tx + 16;
        auto relb = [&](int trow, int dd) -> float {
            const int a = dd < 0 ? -dd : dd;
            const int f = f0s[a];
            const float r1 = Ss[trow][f];
            const float r2 = Ss[trow][17 + f];
            return r1 + (dd > 0 ? r2 : (dd < 0 ? -r2 : 0.f));
        };
        float lg00 = d00 + cbs[tx]      + relb(ty,      sg0 - tg0);
        float lg01 = d01 + cbs[tx + 16] + relb(ty,      sg1 - tg0);
        float lg10 = d10 + cbs[tx]      + relb(ty + 16, sg0 - tg1);
        float lg11 = d11 + cbs[tx + 16] + relb(ty + 16, sg1 - tg1);
        float mt0 = fmaxf(lg00, lg01), mt1 = fmaxf(lg10, lg11);
#pragma unroll
        for (int off = 1; off < 16; off <<= 1) {
            mt0 = fmaxf(mt0, __shfl_xor(mt0, off, 16));
            mt1 = fmaxf(mt1, __shfl_xor(mt1, off, 16));
        }
        const float mn0 = fmaxf(m0, mt0), mn1 = fmaxf(m1, mt1);
        const float p00 = expf(lg00 - mn0), p01 = expf(lg01 - mn0);
        const float p10 = expf(lg10 - mn1), p11 = expf(lg11 - mn1);
        float st0 = p00 + p01, st1 = p10 + p11;
#pragma unroll
        for (int off = 1; off < 16; off <<= 1) {
            st0 += __shfl_xor(st0, off, 16);
            st1 += __shfl_xor(st1, off, 16);
        }
        const float sc0 = expf(m0 - mn0), sc1 = expf(m1 - mn1);
        l0 = l0 * sc0 + st0; l1 = l1 * sc1 + st1;
        m0 = mn0; m1 = mn1;
#pragma unroll
        for (int j = 0; j < 6; ++j) { a0[j] *= sc0; a1[j] *= sc1; }
        ps[ty][tx] = p00; ps[ty][tx + 16] = p01;
        ps[ty + 16][tx] = p10; ps[ty + 16][tx + 16] = p11;
        __syncthreads();
#pragma unroll
        for (int s4 = 0; s4 < 32; s4 += 4) {
            const float4 pa = *(const float4*)&ps[ty][s4];
            const float4 pb = *(const float4*)&ps[ty + 16][s4];
            const float pav[4] = {pa.x, pa.y, pa.z, pa.w};
            const float pbv[4] = {pb.x, pb.y, pb.z, pb.w};
#pragma unroll
            for (int u = 0; u < 4; ++u) {
                const float* vrow = &vs[s4 + u][tx * 6];
                const float2 w0 = *(const float2*)(vrow);
                const float2 w1 = *(const float2*)(vrow + 2);
                const float2 w2 = *(const float2*)(vrow + 4);
                a0[0] += pav[u] * w0.x; a0[1] += pav[u] * w0.y;
                a0[2] += pav[u] * w1.x; a0[3] += pav[u] * w1.y;
                a0[4] += pav[u] * w2.x; a0[5] += pav[u] * w2.y;
                a1[0] += pbv[u] * w0.x; a1[1] += pbv[u] * w0.y;
                a1[2] += pbv[u] * w1.x; a1[3] += pbv[u] * w1.y;
                a1[4] += pbv[u] * w2.x; a1[5] += pbv[u] * w2.y;
            }
        }
    }
    const float inv0 = 1.f / l0, inv1 = 1.f / l1;
    float* pr0 = P + ((size_t)b * Tn + t0 + ty) * Dn + h * Vn + tx * 6;
    float* pr1 = P + ((size_t)b * Tn + t0 + ty + 16) * Dn + h * Vn + tx * 6;
#pragma unroll
    for (int j = 0; j < 6; ++j) { pr0[j] = a0[j] * inv0; pr1[j] = a1[j] * inv1; }
}

// ---------------- output projection ----------------
__global__ __launch_bounds__(256) void out_kernel(
    const float* __restrict__ Pm, const float* __restrict__ Wo,
    const float* __restrict__ bo, float* __restrict__ out) {
    __shared__ __attribute__((aligned(16))) float As[16][68];
    __shared__ __attribute__((aligned(16))) float Bs[16][68];
    const int tid = threadIdx.x;
    const int tx = tid & 15, ty = tid >> 4;
    const int rowBase = blockIdx.y * 64;
    const int colBase = blockIdx.x * 64;
    const int lrow = tid >> 2, lc4 = (tid & 3) << 2;
    const int brow = tid >> 4, bc4 = (tid & 15) << 2;
    float acc[4][4] = {};
    for (int k0 = 0; k0 < Dn; k0 += 16) {
        const float4 av = *(const float4*)&Pm[(size_t)(rowBase + lrow) * Dn + k0 + lc4];
        const float4 bv = *(const float4*)&Wo[(size_t)(k0 + brow) * Dn + colBase + bc4];
        __syncthreads();
        As[lc4 + 0][lrow] = av.x; As[lc4 + 1][lrow] = av.y;
        As[lc4 + 2][lrow] = av.z; As[lc4 + 3][lrow] = av.w;
        *(float4*)&Bs[brow][bc4] = bv;
        __syncthreads();
#pragma unroll
        for (int kk = 0; kk < 16; ++kk) {
            const float4 a4 = *(const float4*)&As[kk][ty << 2];
            const float4 b4 = *(const float4*)&Bs[kk][tx << 2];
            const float aa[4] = {a4.x, a4.y, a4.z, a4.w};
            const float bb[4] = {b4.x, b4.y, b4.z, b4.w};
#pragma unroll
            for (int i = 0; i < 4; ++i)
#pragma unroll
                for (int j = 0; j < 4; ++j) acc[i][j] += aa[i] * bb[j];
        }
    }
#pragma unroll
    for (int i = 0; i < 4; ++i) {
        const int n = rowBase + ty * 4 + i;
#pragma unroll
        for (int j = 0; j < 4; ++j) {
            const int gc = colBase + tx * 4 + j;
            out[(size_t)n * Dn + gc] = acc[i][j] + bo[gc];
        }
    }
}

extern "C" void kernel_launch(void* const* d_in, const int* in_sizes, int n_in,
                              void* d_out, int out_size, void* d_ws, size_t ws_size,
                              hipStream_t stream) {
    (void)in_sizes; (void)n_in; (void)out_size; (void)ws_size;
    const float* x   = (const float*)d_in[0];
    const float* Wq  = (const float*)d_in[1];
    const float* Wk  = (const float*)d_in[2];
    const float* Wv  = (const float*)d_in[3];
    const float* Wrk = (const float*)d_in[4];
    const float* rwb = (const float*)d_in[5];   // r_w_bias
    const float* rrb = (const float*)d_in[6];   // r_r_bias
    const float* Wo  = (const float*)d_in[7];
    const float* bo  = (const float*)d_in[8];
    float* out = (float*)d_out;

    float* ws   = (float*)d_ws;
    float* qh   = ws;                                  // [B,H,T,64]
    float* kh   = qh   + (size_t)Bn * Hn * Tn * Kn;    // [B,H,T,64]
    float* vh   = kh   + (size_t)Bn * Hn * Tn * Kn;    // [B,H,T,96]
    float* Sb   = vh   + (size_t)Bn * Hn * Tn * Vn;    // [B,H,T,34]
    float* cbuf = Sb   + (size_t)Bn * Hn * Tn * 34;    // [B,H,T]
    float* Pm   = cbuf + (size_t)Bn * Hn * Tn;         // [B,T,768]
    int*   f0t  = (int*)(Pm + (size_t)Bn * Tn * Dn);   // [2048]

    f0_kernel<<<dim3((Tn + 255) / 256), 256, 0, stream>>>(f0t);
    proj_kernel<<<dim3(28, 64), 256, 0, stream>>>(x, Wq, Wk, Wv, qh, kh, vh);
    bias_kernel<<<dim3(Tn / 32, Bn * Hn), 256, 0, stream>>>(qh, kh, Wrk, rwb, rrb, Sb, cbuf);
    attn_kernel<<<dim3(Tn / 32, Bn * Hn), 256, 0, stream>>>(qh, kh, vh, Sb, cbuf, f0t, Pm);
    out_kernel<<<dim3(Dn / 64, (Bn * Tn) / 64), 256, 0, stream>>>(Pm, Wo, bo, out);
}

// Round 2
// 382.866 us; speedup vs baseline: 2.0185x; 2.0185x over previous
//
#include <hip/hip_runtime.h>
#include <hip/hip_bf16.h>
#include <math.h>

static constexpr int Bn = 2, Tn = 2048, Dn = 768, Hn = 8, Kn = 64, Vn = 96;

typedef __bf16 bf16x8 __attribute__((ext_vector_type(8)));
typedef float f32x4 __attribute__((ext_vector_type(4)));

// ---------------- f0 threshold table ----------------
__global__ void f0_kernel(int* __restrict__ f0_tab) {
    int a = blockIdx.x * blockDim.x + threadIdx.x;
    if (a >= Tn) return;
    double pr = exp(log((double)(Tn + 1)) / 16.0);
    double w = 1.0; int cnt = 0;
    for (int i = 0; i < 16; ++i) { w *= pr; if ((w - 1.0) <= (double)a) cnt++; }
    f0_tab[a] = cnt;
}

// ---------------- fused QKV projection (f32 compute, bf16 out) ----------------
// X[4096,768] @ [Wq|Wk|Wv] -> qhb(scaled)/khb [BH,T,64] bf16, vtb [BH,96,T] bf16 (transposed)
__global__ __launch_bounds__(256) void proj_kernel(
    const float* __restrict__ X, const float* __restrict__ Wq,
    const float* __restrict__ Wk, const float* __restrict__ Wv,
    __bf16* __restrict__ qhb, __bf16* __restrict__ khb, __bf16* __restrict__ vtb) {
    __shared__ __attribute__((aligned(16))) float As[16][68];
    __shared__ __attribute__((aligned(16))) float Bs[16][68];
    const int tid = threadIdx.x;
    const int tx = tid & 15, ty = tid >> 4;
    const int rowBase = blockIdx.y * 64;
    const int colBase = blockIdx.x * 64;
    const float* Wsrc; int ldw, cb0;
    if (colBase < 512)       { Wsrc = Wq; ldw = 512; cb0 = colBase; }
    else if (colBase < 1024) { Wsrc = Wk; ldw = 512; cb0 = colBase - 512; }
    else                     { Wsrc = Wv; ldw = 768; cb0 = colBase - 1024; }
    const int lrow = tid >> 2, lc4 = (tid & 3) << 2;
    const int brow = tid >> 4, bc4 = (tid & 15) << 2;
    float acc[4][4] = {};
    for (int k0 = 0; k0 < Dn; k0 += 16) {
        const float4 av = *(const float4*)&X[(size_t)(rowBase + lrow) * Dn + k0 + lc4];
        const float4 bv = *(const float4*)&Wsrc[(size_t)(k0 + brow) * ldw + cb0 + bc4];
        __syncthreads();
        As[lc4 + 0][lrow] = av.x; As[lc4 + 1][lrow] = av.y;
        As[lc4 + 2][lrow] = av.z; As[lc4 + 3][lrow] = av.w;
        *(float4*)&Bs[brow][bc4] = bv;
        __syncthreads();
#pragma unroll
        for (int kk = 0; kk < 16; ++kk) {
            const float4 a4 = *(const float4*)&As[kk][ty << 2];
            const float4 b4 = *(const float4*)&Bs[kk][tx << 2];
            const float aa[4] = {a4.x, a4.y, a4.z, a4.w};
            const float bb[4] = {b4.x, b4.y, b4.z, b4.w};
#pragma unroll
            for (int i = 0; i < 4; ++i)
#pragma unroll
                for (int j = 0; j < 4; ++j) acc[i][j] += aa[i] * bb[j];
        }
    }
#pragma unroll
    for (int i = 0; i < 4; ++i) {
        const int n = rowBase + ty * 4 + i;
        const int b = n >> 11, t = n & (Tn - 1);
#pragma unroll
        for (int j = 0; j < 4; ++j) {
            const int gc = colBase + tx * 4 + j;
            const float v = acc[i][j];
            if (gc < 512) {
                qhb[(((size_t)b * Hn + (gc >> 6)) * Tn + t) * Kn + (gc & 63)] = (__bf16)(v * 0.125f);
            } else if (gc < 1024) {
                const int c2 = gc - 512;
                khb[(((size_t)b * Hn + (c2 >> 6)) * Tn + t) * Kn + (c2 & 63)] = (__bf16)v;
            } else {
                const int c3 = gc - 1024;
                vtb[(((size_t)b * Hn + c3 / 96) * 96 + (c3 % 96)) * Tn + t] = (__bf16)v;
            }
        }
    }
}

// ---------------- rel-bias suffix sums S1/S2 and content bias cb ----------------
__global__ __launch_bounds__(256) void bias_kernel(
    const __bf16* __restrict__ qhb, const __bf16* __restrict__ khb,
    const float* __restrict__ Wrk, const float* __restrict__ rwb,
    const float* __restrict__ rrb, float* __restrict__ S, float* __restrict__ cbuf) {
    __shared__ __attribute__((aligned(16))) float qs[32][68];
    __shared__ __attribute__((aligned(16))) float ks[32][68];
    __shared__ __attribute__((aligned(16))) float wr[32][68];
    __shared__ __attribute__((aligned(16))) float rr[64];
    __shared__ __attribute__((aligned(16))) float rw[64];
    __shared__ float us[32][36];
    const int tid = threadIdx.x;
    const int bh = blockIdx.y, h = bh & 7;
    const int t0 = blockIdx.x * 32;
    const int row = tid >> 3, g = tid & 7;
    {
        const bf16x8 qv = *(const bf16x8*)(qhb + ((size_t)bh * Tn + t0 + row) * Kn + g * 8);
        const bf16x8 kv = *(const bf16x8*)(khb + ((size_t)bh * Tn + t0 + row) * Kn + g * 8);
#pragma unroll
        for (int j = 0; j < 8; ++j) { qs[row][g * 8 + j] = (float)qv[j]; ks[row][g * 8 + j] = (float)kv[j]; }
        const float* wrp = Wrk + (size_t)row * (Hn * Kn) + h * Kn + g * 8;
        *(float4*)&wr[row][g * 8]     = *(const float4*)(wrp);
        *(float4*)&wr[row][g * 8 + 4] = *(const float4*)(wrp + 4);
    }
    if (tid < 64) { rr[tid] = rrb[h * Kn + tid]; rw[tid] = rwb[h * Kn + tid]; }
    __syncthreads();
#pragma unroll
    for (int ii = 0; ii < 4; ++ii) {
        const int i = g * 4 + ii;
        float acc = 0.f;
#pragma unroll
        for (int kk = 0; kk < 64; kk += 4) {
            const float4 q4 = *(const float4*)&qs[row][kk];
            const float4 r4 = *(const float4*)&rr[kk];
            const float4 w4 = *(const float4*)&wr[i][kk];
            acc += (q4.x + r4.x) * w4.x + (q4.y + r4.y) * w4.y +
                   (q4.z + r4.z) * w4.z + (q4.w + r4.w) * w4.w;
        }
        us[row][i] = acc;
    }
    float c = 0.f;
#pragma unroll
    for (int j = 0; j < 8; ++j) c += rw[g * 8 + j] * ks[row][g * 8 + j];
    c += __shfl_xor(c, 1, 8); c += __shfl_xor(c, 2, 8); c += __shfl_xor(c, 4, 8);
    if (g == 0) cbuf[(size_t)bh * Tn + t0 + row] = c;
    __syncthreads();
    if (g < 2) {
        float s = 0.f;
        float* dst = S + ((size_t)bh * Tn + t0 + row) * 34 + (g == 0 ? 0 : 17);
        const int base = (g == 0) ? 0 : 16;
        dst[16] = 0.f;
        for (int i = 15; i >= 0; --i) { s += us[row][base + i]; dst[i] = s; }
    }
}

// ---------------- MFMA flash attention with rel-position bias ----------------
// 64 q-rows/block, 4 waves; wave w owns q-rows [t0+16w, +16).
// QK^T: A=Q frag (row=lane&15, k=8*(lane>>4)+i), B=K frag from ks rows.
// D layout: col(key)=lane&15, row(q)=4*(lane>>4)+reg.
__global__ __launch_bounds__(256) void attn_kernel(
    const __bf16* __restrict__ qhb, const __bf16* __restrict__ khb,
    const __bf16* __restrict__ vtb, const float* __restrict__ Sg,
    const float* __restrict__ cbuf, const int* __restrict__ f0t,
    float* __restrict__ P) {
    __shared__ __attribute__((aligned(16))) __bf16 ks[32][72];
    __shared__ __attribute__((aligned(16))) __bf16 vs[96][40];
    __shared__ __attribute__((aligned(16))) __bf16 ps[4][16][40];
    __shared__ float Ss[64][34];
    __shared__ float cbs[32];
    __shared__ unsigned char f0s[Tn];
    const int tid = threadIdx.x;
    const int w = tid >> 6, lane = tid & 63, g = lane >> 4, r16 = lane & 15;
    const int bh = blockIdx.y, b = bh >> 3, h = bh & 7;
    const int t0 = blockIdx.x * 64;

    for (int idx = tid; idx < 64 * 34; idx += 256)
        Ss[idx / 34][idx % 34] = Sg[((size_t)bh * Tn + t0 + idx / 34) * 34 + idx % 34];
    for (int idx = tid; idx < Tn; idx += 256) f0s[idx] = (unsigned char)f0t[idx];

    // Q fragments held in registers for the whole loop
    const __bf16* qbase = qhb + ((size_t)bh * Tn + t0 + w * 16 + r16) * Kn;
    const bf16x8 qA0 = *(const bf16x8*)(qbase + g * 8);
    const bf16x8 qA1 = *(const bf16x8*)(qbase + 32 + g * 8);

    f32x4 acc[6];
#pragma unroll
    for (int i = 0; i < 6; ++i) acc[i] = (f32x4){0.f, 0.f, 0.f, 0.f};
    float m[4] = {-3.0e38f, -3.0e38f, -3.0e38f, -3.0e38f};
    float l[4] = {0.f, 0.f, 0.f, 0.f};

    // staging indices
    const int krow = tid >> 3, kcol8 = (tid & 7) * 8;   // 256 chunks of 16B (K)
    const int vrow = tid >> 2, vcol8 = (tid & 3) * 8;   // V chunks: tid and tid+256

    uint4 kc, vc0, vc1 = {0, 0, 0, 0};
    float cbv = 0.f;
    const size_t kgbase = (size_t)bh * Tn * Kn;
    const size_t vgbase = (size_t)bh * 96 * Tn;
    // prefetch tile 0
    kc  = *(const uint4*)(khb + kgbase + (size_t)(0 + krow) * Kn + kcol8);
    vc0 = *(const uint4*)(vtb + vgbase + (size_t)vrow * Tn + 0 + vcol8);
    if (tid < 128) vc1 = *(const uint4*)(vtb + vgbase + (size_t)(64 + vrow) * Tn + 0 + vcol8);
    if (tid < 32) cbv = cbuf[(size_t)bh * Tn + 0 + tid];

    for (int it = 0; it < Tn / 32; ++it) {
        const int s0 = it * 32;
        __syncthreads();   // prev tile compute done (also covers Ss/f0s staging)
        *(uint4*)&ks[krow][kcol8] = kc;
        *(uint4*)&vs[vrow][vcol8] = vc0;
        if (tid < 128) *(uint4*)&vs[64 + vrow][vcol8] = vc1;
        if (tid < 32) cbs[tid] = cbv;
        __syncthreads();
        // prefetch next tile (latency hides under compute)
        if (it + 1 < Tn / 32) {
            const int sn = s0 + 32;
            kc  = *(const uint4*)(khb + kgbase + (size_t)(sn + krow) * Kn + kcol8);
            vc0 = *(const uint4*)(vtb + vgbase + (size_t)vrow * Tn + sn + vcol8);
            if (tid < 128) vc1 = *(const uint4*)(vtb + vgbase + (size_t)(64 + vrow) * Tn + sn + vcol8);
            if (tid < 32) cbv = cbuf[(size_t)bh * Tn + sn + tid];
        }
        // ---- QK^T: S[16 q][32 keys] per wave ----
        f32x4 S0 = (f32x4){0.f, 0.f, 0.f, 0.f};
        f32x4 S1 = (f32x4){0.f, 0.f, 0.f, 0.f};
        {
            bf16x8 kb;
            kb = *(const bf16x8*)&ks[r16][g * 8];
            S0 = __builtin_amdgcn_mfma_f32_16x16x32_bf16(qA0, kb, S0, 0, 0, 0);
            kb = *(const bf16x8*)&ks[r16][32 + g * 8];
            S0 = __builtin_amdgcn_mfma_f32_16x16x32_bf16(qA1, kb, S0, 0, 0, 0);
            kb = *(const bf16x8*)&ks[16 + r16][g * 8];
            S1 = __builtin_amdgcn_mfma_f32_16x16x32_bf16(qA0, kb, S1, 0, 0, 0);
            kb = *(const bf16x8*)&ks[16 + r16][32 + g * 8];
            S1 = __builtin_amdgcn_mfma_f32_16x16x32_bf16(qA1, kb, S1, 0, 0, 0);
        }
        const float cb0 = cbs[r16], cb1 = cbs[16 + r16];
        const int sg0 = s0 + r16, sg1 = s0 + 16 + r16;
        float sc[4];
#pragma unroll
        for (int reg = 0; reg < 4; ++reg) {
            const int ql = 4 * g + reg;
            const int tq = t0 + w * 16 + ql;
            const int dd0 = sg0 - tq, dd1 = sg1 - tq;
            const int a0i = dd0 < 0 ? -dd0 : dd0;
            const int a1i = dd1 < 0 ? -dd1 : dd1;
            const int fi0 = f0s[a0i], fi1 = f0s[a1i];
            const float* Srow = Ss[w * 16 + ql];
            const float r2a = Srow[17 + fi0];
            const float r2b = Srow[17 + fi1];
            const float rel0 = Srow[fi0] + (dd0 > 0 ? r2a : (dd0 < 0 ? -r2a : 0.f));
            const float rel1 = Srow[fi1] + (dd1 > 0 ? r2b : (dd1 < 0 ? -r2b : 0.f));
            const float lg0 = S0[reg] + cb0 + rel0;
            const float lg1 = S1[reg] + cb1 + rel1;
            float mt = fmaxf(lg0, lg1);
#pragma unroll
            for (int off = 1; off < 16; off <<= 1) mt = fmaxf(mt, __shfl_xor(mt, off, 16));
            const float mn = fmaxf(m[reg], mt);
            const float p0 = __expf(lg0 - mn), p1 = __expf(lg1 - mn);
            float st = p0 + p1;
#pragma unroll
            for (int off = 1; off < 16; off <<= 1) st += __shfl_xor(st, off, 16);
            sc[reg] = __expf(m[reg] - mn);
            l[reg] = l[reg] * sc[reg] + st;
            m[reg] = mn;
            ps[w][ql][r16] = (__bf16)p0;
            ps[w][ql][16 + r16] = (__bf16)p1;
        }
        // rescale accumulators
#pragma unroll
        for (int vf = 0; vf < 6; ++vf)
#pragma unroll
            for (int reg = 0; reg < 4; ++reg) acc[vf][reg] *= sc[reg];
        // ---- PV: O[16 q][96 v] += P[16][32] * V[32][96] ----
        const bf16x8 pa = *(const bf16x8*)&ps[w][r16][8 * g];
#pragma unroll
        for (int vf = 0; vf < 6; ++vf) {
            const bf16x8 vb = *(const bf16x8*)&vs[r16 + 16 * vf][8 * g];
            acc[vf] = __builtin_amdgcn_mfma_f32_16x16x32_bf16(pa, vb, acc[vf], 0, 0, 0);
        }
    }
    float invl[4];
#pragma unroll
    for (int reg = 0; reg < 4; ++reg) invl[reg] = 1.f / l[reg];
#pragma unroll
    for (int vf = 0; vf < 6; ++vf) {
#pragma unroll
        for (int reg = 0; reg < 4; ++reg) {
            const int t = t0 + w * 16 + 4 * g + reg;
            P[((size_t)b * Tn + t) * Dn + h * Vn + r16 + 16 * vf] = acc[vf][reg] * invl[reg];
        }
    }
}

// ---------------- output projection ----------------
__global__ __launch_bounds__(256) void out_kernel(
    const float* __restrict__ Pm, const float* __restrict__ Wo,
    const float* __restrict__ bo, float* __restrict__ out) {
    __shared__ __attribute__((aligned(16))) float As[16][68];
    __shared__ __attribute__((aligned(16))) float Bs[16][68];
    const int tid = threadIdx.x;
    const int tx = tid & 15, ty = tid >> 4;
    const int rowBase = blockIdx.y * 64;
    const int colBase = blockIdx.x * 64;
    const int lrow = tid >> 2, lc4 = (tid & 3) << 2;
    const int brow = tid >> 4, bc4 = (tid & 15) << 2;
    float acc[4][4] = {};
    for (int k0 = 0; k0 < Dn; k0 += 16) {
        const float4 av = *(const float4*)&Pm[(size_t)(rowBase + lrow) * Dn + k0 + lc4];
        const float4 bv = *(const float4*)&Wo[(size_t)(k0 + brow) * Dn + colBase + bc4];
        __syncthreads();
        As[lc4 + 0][lrow] = av.x; As[lc4 + 1][lrow] = av.y;
        As[lc4 + 2][lrow] = av.z; As[lc4 + 3][lrow] = av.w;
        *(float4*)&Bs[brow][bc4] = bv;
        __syncthreads();
#pragma unroll
        for (int kk = 0; kk < 16; ++kk) {
            const float4 a4 = *(const float4*)&As[kk][ty << 2];
            const float4 b4 = *(const float4*)&Bs[kk][tx << 2];
            const float aa[4] = {a4.x, a4.y, a4.z, a4.w};
            const float bb[4] = {b4.x, b4.y, b4.z, b4.w};
#pragma unroll
            for (int i = 0; i < 4; ++i)
#pragma unroll
                for (int j = 0; j < 4; ++j) acc[i][j] += aa[i] * bb[j];
        }
    }
#pragma unroll
    for (int i = 0; i < 4; ++i) {
        const int n = rowBase + ty * 4 + i;
#pragma unroll
        for (int j = 0; j < 4; ++j) {
            const int gc = colBase + tx * 4 + j;
            out[(size_t)n * Dn + gc] = acc[i][j] + bo[gc];
        }
    }
}

extern "C" void kernel_launch(void* const* d_in, const int* in_sizes, int n_in,
                              void* d_out, int out_size, void* d_ws, size_t ws_size,
                              hipStream_t stream) {
    (void)in_sizes; (void)n_in; (void)out_size; (void)ws_size;
    const float* x   = (const float*)d_in[0];
    const float* Wq  = (const float*)d_in[1];
    const float* Wk  = (const float*)d_in[2];
    const float* Wv  = (const float*)d_in[3];
    const float* Wrk = (const float*)d_in[4];
    const float* rwb = (const float*)d_in[5];
    const float* rrb = (const float*)d_in[6];
    const float* Wo  = (const float*)d_in[7];
    const float* bo  = (const float*)d_in[8];
    float* out = (float*)d_out;

    float* ws   = (float*)d_ws;
    float* Pm   = ws;                                   // [B,T,768] f32
    float* Sb   = Pm + (size_t)Bn * Tn * Dn;            // [BH,T,34] f32
    float* cbuf = Sb + (size_t)Bn * Hn * Tn * 34;       // [BH,T] f32
    int*   f0t  = (int*)(cbuf + (size_t)Bn * Hn * Tn);  // [2048]
    __bf16* qhb = (__bf16*)(f0t + Tn);                  // [BH,T,64] bf16
    __bf16* khb = qhb + (size_t)Bn * Hn * Tn * Kn;      // [BH,T,64] bf16
    __bf16* vtb = khb + (size_t)Bn * Hn * Tn * Kn;      // [BH,96,T] bf16 (transposed)

    f0_kernel<<<dim3((Tn + 255) / 256), 256, 0, stream>>>(f0t);
    proj_kernel<<<dim3(28, 64), 256, 0, stream>>>(x, Wq, Wk, Wv, qhb, khb, vtb);
    bias_kernel<<<dim3(Tn / 32, Bn * Hn), 256, 0, stream>>>(qhb, khb, Wrk, rwb, rrb, Sb, cbuf);
    attn_kernel<<<dim3(Tn / 64, Bn * Hn), 256, 0, stream>>>(qhb, khb, vtb, Sb, cbuf, f0t, Pm);
    out_kernel<<<dim3(Dn / 64, (Bn * Tn) / 64), 256, 0, stream>>>(Pm, Wo, bo, out);
}

// Round 3
// 235.151 us; speedup vs baseline: 3.2865x; 1.6282x over previous
//
#include <hip/hip_runtime.h>
#include <hip/hip_bf16.h>
#include <math.h>

static constexpr int Bn = 2, Tn = 2048, Dn = 768, Hn = 8, Kn = 64, Vn = 96;

typedef __bf16 bf16x8 __attribute__((ext_vector_type(8)));
typedef __bf16 bf16x4v __attribute__((ext_vector_type(4)));
typedef float f32x4 __attribute__((ext_vector_type(4)));

// ---------------- f0 threshold table ----------------
__global__ void f0_kernel(int* __restrict__ f0_tab) {
    int a = blockIdx.x * blockDim.x + threadIdx.x;
    if (a >= Tn) return;
    double pr = exp(log((double)(Tn + 1)) / 16.0);
    double w = 1.0; int cnt = 0;
    for (int i = 0; i < 16; ++i) { w *= pr; if ((w - 1.0) <= (double)a) cnt++; }
    f0_tab[a] = cnt;
}

// ---------------- cast x -> bf16 ----------------
__global__ __launch_bounds__(256) void castx_kernel(
    const float* __restrict__ x, __bf16* __restrict__ xb, int n4) {
    int i = blockIdx.x * 256 + threadIdx.x;
    const int stride = gridDim.x * 256;
    for (; i < n4; i += stride) {
        const float4 v = ((const float4*)x)[i];
        bf16x4v o; o[0] = (__bf16)v.x; o[1] = (__bf16)v.y; o[2] = (__bf16)v.z; o[3] = (__bf16)v.w;
        ((bf16x4v*)xb)[i] = o;
    }
}

// ---------------- transpose + cast: WT[n][k] = W[k][n], W is [K][N] f32 ----------------
__global__ __launch_bounds__(256) void transpose_kernel(
    const float* __restrict__ W, __bf16* __restrict__ WT, int Kd, int Nd) {
    __shared__ float tile[32][33];
    const int n0 = blockIdx.x * 32, k0 = blockIdx.y * 32;
    const int tx = threadIdx.x & 31, ty8 = threadIdx.x >> 5;
    for (int r = ty8; r < 32; r += 8)
        tile[r][tx] = W[(size_t)(k0 + r) * Nd + n0 + tx];
    __syncthreads();
    for (int r = ty8; r < 32; r += 8)
        WT[(size_t)(n0 + r) * Kd + k0 + tx] = (__bf16)tile[tx][r];
}

// ---------------- bf16 MFMA GEMM: C[128x128/block] = A[M][Kd] @ BT[N][Kd]^T ----------------
// mode 0: proj epilogue (scatter to qhb/khb/vtb)   mode 1: out epilogue (+bias, f32)
__global__ __launch_bounds__(256) void gemm_kernel(
    const __bf16* __restrict__ A, const __bf16* __restrict__ BT, int Kd, int mode,
    __bf16* __restrict__ qhb, __bf16* __restrict__ khb, __bf16* __restrict__ vtb,
    float* __restrict__ outp, const float* __restrict__ bo) {
    __shared__ __attribute__((aligned(16))) __bf16 smem[2][2][128 * 32];
    const int tid = threadIdx.x;
    const int w = tid >> 6, lane = tid & 63, g = lane >> 4, r16 = lane & 15;
    const int wr = w >> 1, wc = w & 1;
    const int rowBase = blockIdx.y * 128, colBase = blockIdx.x * 128;
    const int NK = Kd >> 5;

    // staging: thread covers (srow0, part) and (srow0+64, part), 16B each, A and B
    const int srow0 = tid >> 2, part = tid & 3;
    const size_t Aoff0 = (size_t)(rowBase + srow0) * Kd + part * 8;
    const size_t Aoff1 = (size_t)(rowBase + 64 + srow0) * Kd + part * 8;
    const size_t Boff0 = (size_t)(colBase + srow0) * Kd + part * 8;
    const size_t Boff1 = (size_t)(colBase + 64 + srow0) * Kd + part * 8;
    const int sw = (srow0 & 7) << 4;
    const int woff0 = (srow0 * 64 + part * 16) ^ sw;
    const int woff1 = ((64 + srow0) * 64 + part * 16) ^ sw;   // (64+srow0)&7 == srow0&7

    int aoff[4], boff[4];
#pragma unroll
    for (int i = 0; i < 4; ++i) {
        const int rowA = wr * 64 + i * 16 + r16;
        aoff[i] = (rowA * 64 + g * 16) ^ ((rowA & 7) << 4);
        const int rowB = wc * 64 + i * 16 + r16;
        boff[i] = (rowB * 64 + g * 16) ^ ((rowB & 7) << 4);
    }

    f32x4 acc[4][4];
#pragma unroll
    for (int i = 0; i < 4; ++i)
#pragma unroll
        for (int j = 0; j < 4; ++j) acc[i][j] = (f32x4){0.f, 0.f, 0.f, 0.f};

    uint4 ar0 = *(const uint4*)(A + Aoff0);
    uint4 ar1 = *(const uint4*)(A + Aoff1);
    uint4 br0 = *(const uint4*)(BT + Boff0);
    uint4 br1 = *(const uint4*)(BT + Boff1);
    {
        char* Ab = (char*)&smem[0][0][0];
        char* Bb = (char*)&smem[0][1][0];
        *(uint4*)(Ab + woff0) = ar0; *(uint4*)(Ab + woff1) = ar1;
        *(uint4*)(Bb + woff0) = br0; *(uint4*)(Bb + woff1) = br1;
    }
    __syncthreads();
    int cur = 0;
    for (int kt = 0; kt < NK; ++kt) {
        if (kt + 1 < NK) {
            const size_t kb = (size_t)(kt + 1) * 32;
            ar0 = *(const uint4*)(A + Aoff0 + kb);
            ar1 = *(const uint4*)(A + Aoff1 + kb);
            br0 = *(const uint4*)(BT + Boff0 + kb);
            br1 = *(const uint4*)(BT + Boff1 + kb);
        }
        char* Ab = (char*)&smem[cur][0][0];
        char* Bb = (char*)&smem[cur][1][0];
        bf16x8 af[4], bfr[4];
#pragma unroll
        for (int i = 0; i < 4; ++i) af[i] = *(const bf16x8*)(Ab + aoff[i]);
#pragma unroll
        for (int j = 0; j < 4; ++j) bfr[j] = *(const bf16x8*)(Bb + boff[j]);
#pragma unroll
        for (int i = 0; i < 4; ++i)
#pragma unroll
            for (int j = 0; j < 4; ++j)
                acc[i][j] = __builtin_amdgcn_mfma_f32_16x16x32_bf16(af[i], bfr[j], acc[i][j], 0, 0, 0);
        if (kt + 1 < NK) {
            char* An = (char*)&smem[cur ^ 1][0][0];
            char* Bpn = (char*)&smem[cur ^ 1][1][0];
            *(uint4*)(An + woff0) = ar0; *(uint4*)(An + woff1) = ar1;
            *(uint4*)(Bpn + woff0) = br0; *(uint4*)(Bpn + woff1) = br1;
        }
        __syncthreads();
        cur ^= 1;
    }
    // ---- epilogue ----
    if (mode == 0) {
#pragma unroll
        for (int i = 0; i < 4; ++i)
#pragma unroll
            for (int j = 0; j < 4; ++j)
#pragma unroll
                for (int reg = 0; reg < 4; ++reg) {
                    const int row = rowBase + wr * 64 + i * 16 + 4 * g + reg;
                    const int col = colBase + wc * 64 + j * 16 + r16;
                    const float v = acc[i][j][reg];
                    const int b = row >> 11, t = row & (Tn - 1);
                    if (col < 512) {
                        qhb[(((size_t)b * Hn + (col >> 6)) * Tn + t) * Kn + (col & 63)] = (__bf16)(v * 0.125f);
                    } else if (col < 1024) {
                        const int c2 = col - 512;
                        khb[(((size_t)b * Hn + (c2 >> 6)) * Tn + t) * Kn + (c2 & 63)] = (__bf16)v;
                    } else {
                        const int c3 = col - 1024;
                        vtb[(((size_t)b * Hn + c3 / 96) * 96 + c3 % 96) * (size_t)Tn + t] = (__bf16)v;
                    }
                }
    } else {
#pragma unroll
        for (int i = 0; i < 4; ++i)
#pragma unroll
            for (int j = 0; j < 4; ++j)
#pragma unroll
                for (int reg = 0; reg < 4; ++reg) {
                    const int row = rowBase + wr * 64 + i * 16 + 4 * g + reg;
                    const int col = colBase + wc * 64 + j * 16 + r16;
                    outp[(size_t)row * Dn + col] = acc[i][j][reg] + bo[col];
                }
    }
}

// ---------------- rel-bias suffix sums S1/S2 and content bias cb ----------------
__global__ __launch_bounds__(256) void bias_kernel(
    const __bf16* __restrict__ qhb, const __bf16* __restrict__ khb,
    const float* __restrict__ Wrk, const float* __restrict__ rwb,
    const float* __restrict__ rrb, float* __restrict__ S, float* __restrict__ cbuf) {
    __shared__ __attribute__((aligned(16))) float qs[32][68];
    __shared__ __attribute__((aligned(16))) float ks[32][68];
    __shared__ __attribute__((aligned(16))) float wr[32][68];
    __shared__ __attribute__((aligned(16))) float rr[64];
    __shared__ __attribute__((aligned(16))) float rw[64];
    __shared__ float us[32][36];
    const int tid = threadIdx.x;
    const int bh = blockIdx.y, h = bh & 7;
    const int t0 = blockIdx.x * 32;
    const int row = tid >> 3, g = tid & 7;
    {
        const bf16x8 qv = *(const bf16x8*)(qhb + ((size_t)bh * Tn + t0 + row) * Kn + g * 8);
        const bf16x8 kv = *(const bf16x8*)(khb + ((size_t)bh * Tn + t0 + row) * Kn + g * 8);
#pragma unroll
        for (int j = 0; j < 8; ++j) { qs[row][g * 8 + j] = (float)qv[j]; ks[row][g * 8 + j] = (float)kv[j]; }
        const float* wrp = Wrk + (size_t)row * (Hn * Kn) + h * Kn + g * 8;
        *(float4*)&wr[row][g * 8]     = *(const float4*)(wrp);
        *(float4*)&wr[row][g * 8 + 4] = *(const float4*)(wrp + 4);
    }
    if (tid < 64) { rr[tid] = rrb[h * Kn + tid]; rw[tid] = rwb[h * Kn + tid]; }
    __syncthreads();
#pragma unroll
    for (int ii = 0; ii < 4; ++ii) {
        const int i = g * 4 + ii;
        float acc = 0.f;
#pragma unroll
        for (int kk = 0; kk < 64; kk += 4) {
            const float4 q4 = *(const float4*)&qs[row][kk];
            const float4 r4 = *(const float4*)&rr[kk];
            const float4 w4 = *(const float4*)&wr[i][kk];
            acc += (q4.x + r4.x) * w4.x + (q4.y + r4.y) * w4.y +
                   (q4.z + r4.z) * w4.z + (q4.w + r4.w) * w4.w;
        }
        us[row][i] = acc;
    }
    float c = 0.f;
#pragma unroll
    for (int j = 0; j < 8; ++j) c += rw[g * 8 + j] * ks[row][g * 8 + j];
    c += __shfl_xor(c, 1, 8); c += __shfl_xor(c, 2, 8); c += __shfl_xor(c, 4, 8);
    if (g == 0) cbuf[(size_t)bh * Tn + t0 + row] = c;
    __syncthreads();
    if (g < 2) {
        float s = 0.f;
        float* dst = S + ((size_t)bh * Tn + t0 + row) * 34 + (g == 0 ? 0 : 17);
        const int base = (g == 0) ? 0 : 16;
        dst[16] = 0.f;
        for (int i = 15; i >= 0; --i) { s += us[row][base + i]; dst[i] = s; }
    }
}

// ---------------- MFMA flash attention with rel-position bias ----------------
__global__ __launch_bounds__(256) void attn_kernel(
    const __bf16* __restrict__ qhb, const __bf16* __restrict__ khb,
    const __bf16* __restrict__ vtb, const float* __restrict__ Sg,
    const float* __restrict__ cbuf, const int* __restrict__ f0t,
    __bf16* __restrict__ P) {
    __shared__ __attribute__((aligned(16))) __bf16 ks[32][72];
    __shared__ __attribute__((aligned(16))) __bf16 vs[96][40];
    __shared__ __attribute__((aligned(16))) __bf16 ps[4][16][40];
    __shared__ float Ss[64][34];
    __shared__ float cbs[32];
    __shared__ unsigned char f0s[Tn];
    const int tid = threadIdx.x;
    const int w = tid >> 6, lane = tid & 63, g = lane >> 4, r16 = lane & 15;
    const int bh = blockIdx.y, b = bh >> 3, h = bh & 7;
    const int t0 = blockIdx.x * 64;

    for (int idx = tid; idx < 64 * 34; idx += 256)
        Ss[idx / 34][idx % 34] = Sg[((size_t)bh * Tn + t0 + idx / 34) * 34 + idx % 34];
    for (int idx = tid; idx < Tn; idx += 256) f0s[idx] = (unsigned char)f0t[idx];

    const __bf16* qbase = qhb + ((size_t)bh * Tn + t0 + w * 16 + r16) * Kn;
    const bf16x8 qA0 = *(const bf16x8*)(qbase + g * 8);
    const bf16x8 qA1 = *(const bf16x8*)(qbase + 32 + g * 8);

    f32x4 acc[6];
#pragma unroll
    for (int i = 0; i < 6; ++i) acc[i] = (f32x4){0.f, 0.f, 0.f, 0.f};
    float m[4] = {-3.0e38f, -3.0e38f, -3.0e38f, -3.0e38f};
    float l[4] = {0.f, 0.f, 0.f, 0.f};

    const int krow = tid >> 3, kcol8 = (tid & 7) * 8;
    const int vrow = tid >> 2, vcol8 = (tid & 3) * 8;

    uint4 kc, vc0, vc1 = {0, 0, 0, 0};
    float cbv = 0.f;
    const size_t kgbase = (size_t)bh * Tn * Kn;
    const size_t vgbase = (size_t)bh * 96 * Tn;
    kc  = *(const uint4*)(khb + kgbase + (size_t)(0 + krow) * Kn + kcol8);
    vc0 = *(const uint4*)(vtb + vgbase + (size_t)vrow * Tn + 0 + vcol8);
    if (tid < 128) vc1 = *(const uint4*)(vtb + vgbase + (size_t)(64 + vrow) * Tn + 0 + vcol8);
    if (tid < 32) cbv = cbuf[(size_t)bh * Tn + 0 + tid];

    for (int it = 0; it < Tn / 32; ++it) {
        const int s0 = it * 32;
        __syncthreads();
        *(uint4*)&ks[krow][kcol8] = kc;
        *(uint4*)&vs[vrow][vcol8] = vc0;
        if (tid < 128) *(uint4*)&vs[64 + vrow][vcol8] = vc1;
        if (tid < 32) cbs[tid] = cbv;
        __syncthreads();
        if (it + 1 < Tn / 32) {
            const int sn = s0 + 32;
            kc  = *(const uint4*)(khb + kgbase + (size_t)(sn + krow) * Kn + kcol8);
            vc0 = *(const uint4*)(vtb + vgbase + (size_t)vrow * Tn + sn + vcol8);
            if (tid < 128) vc1 = *(const uint4*)(vtb + vgbase + (size_t)(64 + vrow) * Tn + sn + vcol8);
            if (tid < 32) cbv = cbuf[(size_t)bh * Tn + sn + tid];
        }
        f32x4 S0 = (f32x4){0.f, 0.f, 0.f, 0.f};
        f32x4 S1 = (f32x4){0.f, 0.f, 0.f, 0.f};
        {
            bf16x8 kb;
            kb = *(const bf16x8*)&ks[r16][g * 8];
            S0 = __builtin_amdgcn_mfma_f32_16x16x32_bf16(qA0, kb, S0, 0, 0, 0);
            kb = *(const bf16x8*)&ks[r16][32 + g * 8];
            S0 = __builtin_amdgcn_mfma_f32_16x16x32_bf16(qA1, kb, S0, 0, 0, 0);
            kb = *(const bf16x8*)&ks[16 + r16][g * 8];
            S1 = __builtin_amdgcn_mfma_f32_16x16x32_bf16(qA0, kb, S1, 0, 0, 0);
            kb = *(const bf16x8*)&ks[16 + r16][32 + g * 8];
            S1 = __builtin_amdgcn_mfma_f32_16x16x32_bf16(qA1, kb, S1, 0, 0, 0);
        }
        const float cb0 = cbs[r16], cb1 = cbs[16 + r16];
        const int sg0 = s0 + r16, sg1 = s0 + 16 + r16;
        float sc[4];
#pragma unroll
        for (int reg = 0; reg < 4; ++reg) {
            const int ql = 4 * g + reg;
            const int tq = t0 + w * 16 + ql;
            const int dd0 = sg0 - tq, dd1 = sg1 - tq;
            const int a0i = dd0 < 0 ? -dd0 : dd0;
            const int a1i = dd1 < 0 ? -dd1 : dd1;
            const int fi0 = f0s[a0i], fi1 = f0s[a1i];
            const float* Srow = Ss[w * 16 + ql];
            const float r2a = Srow[17 + fi0];
            const float r2b = Srow[17 + fi1];
            const float rel0 = Srow[fi0] + (dd0 > 0 ? r2a : (dd0 < 0 ? -r2a : 0.f));
            const float rel1 = Srow[fi1] + (dd1 > 0 ? r2b : (dd1 < 0 ? -r2b : 0.f));
            const float lg0 = S0[reg] + cb0 + rel0;
            const float lg1 = S1[reg] + cb1 + rel1;
            float mt = fmaxf(lg0, lg1);
#pragma unroll
            for (int off = 1; off < 16; off <<= 1) mt = fmaxf(mt, __shfl_xor(mt, off, 16));
            const float mn = fmaxf(m[reg], mt);
            const float p0 = __expf(lg0 - mn), p1 = __expf(lg1 - mn);
            float st = p0 + p1;
#pragma unroll
            for (int off = 1; off < 16; off <<= 1) st += __shfl_xor(st, off, 16);
            sc[reg] = __expf(m[reg] - mn);
            l[reg] = l[reg] * sc[reg] + st;
            m[reg] = mn;
            ps[w][ql][r16] = (__bf16)p0;
            ps[w][ql][16 + r16] = (__bf16)p1;
        }
#pragma unroll
        for (int vf = 0; vf < 6; ++vf)
#pragma unroll
            for (int reg = 0; reg < 4; ++reg) acc[vf][reg] *= sc[reg];
        const bf16x8 pa = *(const bf16x8*)&ps[w][r16][8 * g];
#pragma unroll
        for (int vf = 0; vf < 6; ++vf) {
            const bf16x8 vb = *(const bf16x8*)&vs[r16 + 16 * vf][8 * g];
            acc[vf] = __builtin_amdgcn_mfma_f32_16x16x32_bf16(pa, vb, acc[vf], 0, 0, 0);
        }
    }
    float invl[4];
#pragma unroll
    for (int reg = 0; reg < 4; ++reg) invl[reg] = 1.f / l[reg];
#pragma unroll
    for (int vf = 0; vf < 6; ++vf) {
#pragma unroll
        for (int reg = 0; reg < 4; ++reg) {
            const int t = t0 + w * 16 + 4 * g + reg;
            P[((size_t)b * Tn + t) * Dn + h * Vn + r16 + 16 * vf] = (__bf16)(acc[vf][reg] * invl[reg]);
        }
    }
}

extern "C" void kernel_launch(void* const* d_in, const int* in_sizes, int n_in,
                              void* d_out, int out_size, void* d_ws, size_t ws_size,
                              hipStream_t stream) {
    (void)in_sizes; (void)n_in; (void)out_size; (void)ws_size;
    const float* x   = (const float*)d_in[0];
    const float* Wq  = (const float*)d_in[1];
    const float* Wk  = (const float*)d_in[2];
    const float* Wv  = (const float*)d_in[3];
    const float* Wrk = (const float*)d_in[4];
    const float* rwb = (const float*)d_in[5];
    const float* rrb = (const float*)d_in[6];
    const float* Wo  = (const float*)d_in[7];
    const float* bo  = (const float*)d_in[8];
    float* out = (float*)d_out;

    char* p = (char*)d_ws;
    auto alloc = [&](size_t bytes) { char* r = p; p += (bytes + 255) & ~(size_t)255; return r; };
    float*  Sb   = (float*)alloc((size_t)Bn * Hn * Tn * 34 * 4);
    float*  cbuf = (float*)alloc((size_t)Bn * Hn * Tn * 4);
    int*    f0t  = (int*)alloc((size_t)Tn * 4);
    __bf16* qhb  = (__bf16*)alloc((size_t)Bn * Hn * Tn * Kn * 2);
    __bf16* khb  = (__bf16*)alloc((size_t)Bn * Hn * Tn * Kn * 2);
    __bf16* vtb  = (__bf16*)alloc((size_t)Bn * Hn * 96 * Tn * 2);
    __bf16* Pmb  = (__bf16*)alloc((size_t)Bn * Tn * Dn * 2);
    __bf16* Xb   = (__bf16*)alloc((size_t)Bn * Tn * Dn * 2);
    __bf16* WT   = (__bf16*)alloc((size_t)1792 * 768 * 2);
    __bf16* WoT  = (__bf16*)alloc((size_t)768 * 768 * 2);

    f0_kernel<<<dim3((Tn + 255) / 256), 256, 0, stream>>>(f0t);
    castx_kernel<<<dim3(1536), 256, 0, stream>>>(x, Xb, Bn * Tn * Dn / 4);
    transpose_kernel<<<dim3(16, 24), 256, 0, stream>>>(Wq, WT, 768, 512);
    transpose_kernel<<<dim3(16, 24), 256, 0, stream>>>(Wk, WT + (size_t)512 * 768, 768, 512);
    transpose_kernel<<<dim3(24, 24), 256, 0, stream>>>(Wv, WT + (size_t)1024 * 768, 768, 768);
    transpose_kernel<<<dim3(24, 24), 256, 0, stream>>>(Wo, WoT, 768, 768);
    gemm_kernel<<<dim3(14, 32), 256, 0, stream>>>(Xb, WT, 768, 0, qhb, khb, vtb, nullptr, nullptr);
    bias_kernel<<<dim3(Tn / 32, Bn * Hn), 256, 0, stream>>>(qhb, khb, Wrk, rwb, rrb, Sb, cbuf);
    attn_kernel<<<dim3(Tn / 64, Bn * Hn), 256, 0, stream>>>(qhb, khb, vtb, Sb, cbuf, f0t, Pmb);
    gemm_kernel<<<dim3(6, 32), 256, 0, stream>>>(Pmb, WoT, 768, 1, nullptr, nullptr, nullptr, out, bo);
}

// Round 4
// 179.026 us; speedup vs baseline: 4.3168x; 1.3135x over previous
//
#include <hip/hip_runtime.h>
#include <hip/hip_bf16.h>
#include <math.h>

static constexpr int Bn = 2, Tn = 2048, Dn = 768, Hn = 8, Kn = 64, Vn = 96;

typedef __bf16 bf16x8 __attribute__((ext_vector_type(8)));
typedef __bf16 bf16x4v __attribute__((ext_vector_type(4)));
typedef float f32x4 __attribute__((ext_vector_type(4)));
typedef float f32x16 __attribute__((ext_vector_type(16)));

// fi = #{ i in [1,16] : pr^i - 1 <= a } = floor(log2(a+1) * 16/log2(2049)).
// Boundaries are >=0.088 from integers; float log2 error ~2e-6 << margin 8e-5.
#define F0_SCALE 1.45445233f

// ---------------- cast x -> bf16 ----------------
__global__ __launch_bounds__(256) void castx_kernel(
    const float* __restrict__ x, __bf16* __restrict__ xb, int n4) {
    int i = blockIdx.x * 256 + threadIdx.x;
    const int stride = gridDim.x * 256;
    for (; i < n4; i += stride) {
        const float4 v = ((const float4*)x)[i];
        bf16x4v o; o[0] = (__bf16)v.x; o[1] = (__bf16)v.y; o[2] = (__bf16)v.z; o[3] = (__bf16)v.w;
        ((bf16x4v*)xb)[i] = o;
    }
}

// ---------------- transpose + cast: WT[n][k] = W[k][n], W is [K][N] f32 ----------------
__global__ __launch_bounds__(256) void transpose_kernel(
    const float* __restrict__ W, __bf16* __restrict__ WT, int Kd, int Nd) {
    __shared__ float tile[32][33];
    const int n0 = blockIdx.x * 32, k0 = blockIdx.y * 32;
    const int tx = threadIdx.x & 31, ty8 = threadIdx.x >> 5;
    for (int r = ty8; r < 32; r += 8)
        tile[r][tx] = W[(size_t)(k0 + r) * Nd + n0 + tx];
    __syncthreads();
    for (int r = ty8; r < 32; r += 8)
        WT[(size_t)(n0 + r) * Kd + k0 + tx] = (__bf16)tile[tx][r];
}

// ---------------- bf16 MFMA GEMM: C[128x128/block] = A[M][Kd] @ BT[N][Kd]^T ----------------
__global__ __launch_bounds__(256) void gemm_kernel(
    const __bf16* __restrict__ A, const __bf16* __restrict__ BT, int Kd, int mode,
    __bf16* __restrict__ qhb, __bf16* __restrict__ khb, __bf16* __restrict__ vtb,
    float* __restrict__ outp, const float* __restrict__ bo) {
    __shared__ __attribute__((aligned(16))) __bf16 smem[2][2][128 * 32];
    const int tid = threadIdx.x;
    const int w = tid >> 6, lane = tid & 63, g = lane >> 4, r16 = lane & 15;
    const int wr = w >> 1, wc = w & 1;
    const int rowBase = blockIdx.y * 128, colBase = blockIdx.x * 128;
    const int NK = Kd >> 5;

    const int srow0 = tid >> 2, part = tid & 3;
    const size_t Aoff0 = (size_t)(rowBase + srow0) * Kd + part * 8;
    const size_t Aoff1 = (size_t)(rowBase + 64 + srow0) * Kd + part * 8;
    const size_t Boff0 = (size_t)(colBase + srow0) * Kd + part * 8;
    const size_t Boff1 = (size_t)(colBase + 64 + srow0) * Kd + part * 8;
    const int sw = (srow0 & 7) << 4;
    const int woff0 = (srow0 * 64 + part * 16) ^ sw;
    const int woff1 = ((64 + srow0) * 64 + part * 16) ^ sw;

    int aoff[4], boff[4];
#pragma unroll
    for (int i = 0; i < 4; ++i) {
        const int rowA = wr * 64 + i * 16 + r16;
        aoff[i] = (rowA * 64 + g * 16) ^ ((rowA & 7) << 4);
        const int rowB = wc * 64 + i * 16 + r16;
        boff[i] = (rowB * 64 + g * 16) ^ ((rowB & 7) << 4);
    }

    f32x4 acc[4][4];
#pragma unroll
    for (int i = 0; i < 4; ++i)
#pragma unroll
        for (int j = 0; j < 4; ++j) acc[i][j] = (f32x4){0.f, 0.f, 0.f, 0.f};

    uint4 ar0 = *(const uint4*)(A + Aoff0);
    uint4 ar1 = *(const uint4*)(A + Aoff1);
    uint4 br0 = *(const uint4*)(BT + Boff0);
    uint4 br1 = *(const uint4*)(BT + Boff1);
    {
        char* Ab = (char*)&smem[0][0][0];
        char* Bb = (char*)&smem[0][1][0];
        *(uint4*)(Ab + woff0) = ar0; *(uint4*)(Ab + woff1) = ar1;
        *(uint4*)(Bb + woff0) = br0; *(uint4*)(Bb + woff1) = br1;
    }
    __syncthreads();
    int cur = 0;
    for (int kt = 0; kt < NK; ++kt) {
        if (kt + 1 < NK) {
            const size_t kb = (size_t)(kt + 1) * 32;
            ar0 = *(const uint4*)(A + Aoff0 + kb);
            ar1 = *(const uint4*)(A + Aoff1 + kb);
            br0 = *(const uint4*)(BT + Boff0 + kb);
            br1 = *(const uint4*)(BT + Boff1 + kb);
        }
        char* Ab = (char*)&smem[cur][0][0];
        char* Bb = (char*)&smem[cur][1][0];
        bf16x8 af[4], bfr[4];
#pragma unroll
        for (int i = 0; i < 4; ++i) af[i] = *(const bf16x8*)(Ab + aoff[i]);
#pragma unroll
        for (int j = 0; j < 4; ++j) bfr[j] = *(const bf16x8*)(Bb + boff[j]);
#pragma unroll
        for (int i = 0; i < 4; ++i)
#pragma unroll
            for (int j = 0; j < 4; ++j)
                acc[i][j] = __builtin_amdgcn_mfma_f32_16x16x32_bf16(af[i], bfr[j], acc[i][j], 0, 0, 0);
        if (kt + 1 < NK) {
            char* An = (char*)&smem[cur ^ 1][0][0];
            char* Bpn = (char*)&smem[cur ^ 1][1][0];
            *(uint4*)(An + woff0) = ar0; *(uint4*)(An + woff1) = ar1;
            *(uint4*)(Bpn + woff0) = br0; *(uint4*)(Bpn + woff1) = br1;
        }
        __syncthreads();
        cur ^= 1;
    }
    if (mode == 0) {
#pragma unroll
        for (int i = 0; i < 4; ++i)
#pragma unroll
            for (int j = 0; j < 4; ++j)
#pragma unroll
                for (int reg = 0; reg < 4; ++reg) {
                    const int row = rowBase + wr * 64 + i * 16 + 4 * g + reg;
                    const int col = colBase + wc * 64 + j * 16 + r16;
                    const float v = acc[i][j][reg];
                    const int b = row >> 11, t = row & (Tn - 1);
                    if (col < 512) {
                        qhb[(((size_t)b * Hn + (col >> 6)) * Tn + t) * Kn + (col & 63)] = (__bf16)(v * 0.125f);
                    } else if (col < 1024) {
                        const int c2 = col - 512;
                        khb[(((size_t)b * Hn + (c2 >> 6)) * Tn + t) * Kn + (c2 & 63)] = (__bf16)v;
                    } else {
                        const int c3 = col - 1024;
                        vtb[(((size_t)b * Hn + c3 / 96) * 96 + c3 % 96) * (size_t)Tn + t] = (__bf16)v;
                    }
                }
    } else {
#pragma unroll
        for (int i = 0; i < 4; ++i)
#pragma unroll
            for (int j = 0; j < 4; ++j)
#pragma unroll
                for (int reg = 0; reg < 4; ++reg) {
                    const int row = rowBase + wr * 64 + i * 16 + 4 * g + reg;
                    const int col = colBase + wc * 64 + j * 16 + r16;
                    outp[(size_t)row * Dn + col] = acc[i][j][reg] + bo[col];
                }
    }
}

// ---------------- rel-bias tables Rp/Rn/S1[0] (stride 35) and content bias cb (bf16) ----------------
__global__ __launch_bounds__(256) void bias_kernel(
    const __bf16* __restrict__ qhb, const __bf16* __restrict__ khb,
    const float* __restrict__ Wrk, const float* __restrict__ rwb,
    const float* __restrict__ rrb, float* __restrict__ S, __bf16* __restrict__ cbb) {
    __shared__ __attribute__((aligned(16))) float qs[32][68];
    __shared__ __attribute__((aligned(16))) float ks[32][68];
    __shared__ __attribute__((aligned(16))) float wr[32][68];
    __shared__ __attribute__((aligned(16))) float rr[64];
    __shared__ __attribute__((aligned(16))) float rw[64];
    __shared__ float us[32][36];
    const int tid = threadIdx.x;
    const int bh = blockIdx.y, h = bh & 7;
    const int t0 = blockIdx.x * 32;
    const int row = tid >> 3, g = tid & 7;
    {
        const bf16x8 qv = *(const bf16x8*)(qhb + ((size_t)bh * Tn + t0 + row) * Kn + g * 8);
        const bf16x8 kv = *(const bf16x8*)(khb + ((size_t)bh * Tn + t0 + row) * Kn + g * 8);
#pragma unroll
        for (int j = 0; j < 8; ++j) { qs[row][g * 8 + j] = (float)qv[j]; ks[row][g * 8 + j] = (float)kv[j]; }
        const float* wrp = Wrk + (size_t)row * (Hn * Kn) + h * Kn + g * 8;
        *(float4*)&wr[row][g * 8]     = *(const float4*)(wrp);
        *(float4*)&wr[row][g * 8 + 4] = *(const float4*)(wrp + 4);
    }
    if (tid < 64) { rr[tid] = rrb[h * Kn + tid]; rw[tid] = rwb[h * Kn + tid]; }
    __syncthreads();
#pragma unroll
    for (int ii = 0; ii < 4; ++ii) {
        const int i = g * 4 + ii;
        float acc = 0.f;
#pragma unroll
        for (int kk = 0; kk < 64; kk += 4) {
            const float4 q4 = *(const float4*)&qs[row][kk];
            const float4 r4 = *(const float4*)&rr[kk];
            const float4 w4 = *(const float4*)&wr[i][kk];
            acc += (q4.x + r4.x) * w4.x + (q4.y + r4.y) * w4.y +
                   (q4.z + r4.z) * w4.z + (q4.w + r4.w) * w4.w;
        }
        us[row][i] = acc;
    }
    float c = 0.f;
#pragma unroll
    for (int j = 0; j < 8; ++j) c += rw[g * 8 + j] * ks[row][g * 8 + j];
    c += __shfl_xor(c, 1, 8); c += __shfl_xor(c, 2, 8); c += __shfl_xor(c, 4, 8);
    if (g == 0) cbb[(size_t)bh * Tn + t0 + row] = (__bf16)c;
    __syncthreads();
    if (g == 0) {
        float* dst = S + ((size_t)bh * Tn + t0 + row) * 35;
        float s1 = 0.f, s2 = 0.f;
        dst[16] = 0.f; dst[33] = 0.f;
        for (int i = 15; i >= 0; --i) {
            s1 += us[row][i]; s2 += us[row][16 + i];
            dst[i] = s1 + s2;        // d > 0
            dst[17 + i] = s1 - s2;   // d < 0
        }
        dst[34] = s1;                // d == 0
    }
}

// ---------------- MFMA flash attention, swapped layout + intra-block split-KV ----------------
// Block: 32 q-rows, 4 waves; wave w owns keys [w*512, w*512+512).
// QK^T: S^T = K*Q^T via 32x32x16; lane: q = lane&31 (col), 16 key-regs (rows).
// cb folded via extra MFMA with K~[64]=cb[s], Q~[64]=1.
__global__ __launch_bounds__(256, 4) void attn_kernel(
    const __bf16* __restrict__ qhb, const __bf16* __restrict__ khb,
    const __bf16* __restrict__ vtb, const float* __restrict__ Sg,
    const __bf16* __restrict__ cbb, __bf16* __restrict__ P) {
    __shared__ float SsL[32][35];
    __shared__ float mlbuf[4][32][2];
    __shared__ float linv[32];
    __shared__ float obufA[32][97];
    __shared__ float obufB[32][97];
    const int tid = threadIdx.x;
    const int w = tid >> 6, lane = tid & 63;
    const int q = lane & 31, hi = lane >> 5;
    const int bh = blockIdx.y, b = bh >> 3, h = bh & 7;
    const int t0 = blockIdx.x * 32;

    for (int idx = tid; idx < 32 * 35; idx += 256)
        SsL[idx / 35][idx % 35] = Sg[((size_t)bh * Tn + t0 + idx / 35) * 35 + idx % 35];

    // Q B-fragments (held in registers)
    const __bf16* qrow = qhb + ((size_t)bh * Tn + t0 + q) * Kn + hi * 8;
    bf16x8 qf[4];
#pragma unroll
    for (int kt = 0; kt < 4; ++kt) qf[kt] = *(const bf16x8*)(qrow + kt * 16);
    bf16x8 qe = {};
    if (hi == 0) qe[0] = (__bf16)1.0f;

    f32x16 acc0 = {0.f}, acc1 = {0.f}, acc2 = {0.f};
    float m = -3.0e38f, l = 0.f;

    const size_t kbase = (size_t)bh * Tn * Kn;
    const size_t vbase = (size_t)bh * 96 * Tn;
    const size_t cbase = (size_t)bh * Tn;
    const int sBeg = w * (Tn / 4);

    __syncthreads();   // SsL ready

    for (int itile = 0; itile < Tn / 4 / 32; ++itile) {
        const int s0 = sBeg + itile * 32;
        // ---- QK^T (+cb) ----
        const __bf16* krow = khb + kbase + (size_t)(s0 + q) * Kn + hi * 8;
        f32x16 st = {0.f};
#pragma unroll
        for (int kt = 0; kt < 4; ++kt) {
            const bf16x8 kf = *(const bf16x8*)(krow + kt * 16);
            st = __builtin_amdgcn_mfma_f32_32x32x16_bf16(kf, qf[kt], st, 0, 0, 0);
        }
        {
            bf16x8 ke = {};
            if (hi == 0) ke[0] = cbb[cbase + s0 + q];
            st = __builtin_amdgcn_mfma_f32_32x32x16_bf16(ke, qe, st, 0, 0, 0);
        }
        // ---- rel bias + online softmax (in-register) ----
        const int dbase = s0 - t0 - q;
        float p[16];
        float mt = -3.0e38f;
#pragma unroll
        for (int r = 0; r < 16; ++r) {
            const int kr = (r & 3) + 8 * (r >> 2) + 4 * hi;
            const int d = dbase + kr;
            const int a = d < 0 ? -d : d;
            const int fi = (int)(__log2f((float)(a + 1)) * F0_SCALE);
            const int idx = d > 0 ? fi : (d < 0 ? 17 + fi : 34);
            p[r] = st[r] + SsL[q][idx];
            mt = fmaxf(mt, p[r]);
        }
        mt = fmaxf(mt, __shfl_xor(mt, 32));
        const float mn = fmaxf(m, mt);
        const float sc = __expf(m - mn);
        float ssum = 0.f;
#pragma unroll
        for (int r = 0; r < 16; ++r) { p[r] = __expf(p[r] - mn); ssum += p[r]; }
        ssum += __shfl_xor(ssum, 32);
        l = l * sc + ssum;
        m = mn;
        acc0 *= sc; acc1 *= sc; acc2 *= sc;
        // ---- pack P to bf16 B-fragments (cvt_pk + cross-half exchange) ----
        unsigned int c[8], x[8];
#pragma unroll
        for (int i = 0; i < 8; ++i) {
            union { __bf16 hh[2]; unsigned int u; } uu;
            uu.hh[0] = (__bf16)p[2 * i]; uu.hh[1] = (__bf16)p[2 * i + 1];
            c[i] = uu.u;
        }
#pragma unroll
        for (int i = 0; i < 8; ++i) x[i] = __shfl_xor(c[i], 32);
        union { unsigned int u[4]; bf16x8 v; } B0, B1;
        B0.u[0] = hi ? x[2] : c[0]; B0.u[1] = hi ? x[3] : c[1];
        B0.u[2] = hi ? c[2] : x[0]; B0.u[3] = hi ? c[3] : x[1];
        B1.u[0] = hi ? x[6] : c[4]; B1.u[1] = hi ? x[7] : c[5];
        B1.u[2] = hi ? c[6] : x[4]; B1.u[3] = hi ? c[7] : x[5];
        // ---- PV: O^T += V^T * P^T ----
        {
            const __bf16* vrow = vtb + vbase + (size_t)(0 * 32 + q) * Tn + s0 + hi * 8;
            const bf16x8 vf0 = *(const bf16x8*)(vrow);
            const bf16x8 vf1 = *(const bf16x8*)(vrow + 16);
            acc0 = __builtin_amdgcn_mfma_f32_32x32x16_bf16(vf0, B0.v, acc0, 0, 0, 0);
            acc0 = __builtin_amdgcn_mfma_f32_32x32x16_bf16(vf1, B1.v, acc0, 0, 0, 0);
        }
        {
            const __bf16* vrow = vtb + vbase + (size_t)(1 * 32 + q) * Tn + s0 + hi * 8;
            const bf16x8 vf0 = *(const bf16x8*)(vrow);
            const bf16x8 vf1 = *(const bf16x8*)(vrow + 16);
            acc1 = __builtin_amdgcn_mfma_f32_32x32x16_bf16(vf0, B0.v, acc1, 0, 0, 0);
            acc1 = __builtin_amdgcn_mfma_f32_32x32x16_bf16(vf1, B1.v, acc1, 0, 0, 0);
        }
        {
            const __bf16* vrow = vtb + vbase + (size_t)(2 * 32 + q) * Tn + s0 + hi * 8;
            const bf16x8 vf0 = *(const bf16x8*)(vrow);
            const bf16x8 vf1 = *(const bf16x8*)(vrow + 16);
            acc2 = __builtin_amdgcn_mfma_f32_32x32x16_bf16(vf0, B0.v, acc2, 0, 0, 0);
            acc2 = __builtin_amdgcn_mfma_f32_32x32x16_bf16(vf1, B1.v, acc2, 0, 0, 0);
        }
    }

    // ---- flash combine across the 4 waves ----
    if (lane < 32) { mlbuf[w][q][0] = m; mlbuf[w][q][1] = l; }
    __syncthreads();
    const float mstar = fmaxf(fmaxf(mlbuf[0][q][0], mlbuf[1][q][0]),
                              fmaxf(mlbuf[2][q][0], mlbuf[3][q][0]));
    const float wme = __expf(m - mstar);
    if (w == 0 && lane < 32) {
        float ls = 0.f;
#pragma unroll
        for (int ww = 0; ww < 4; ++ww)
            ls += mlbuf[ww][q][1] * __expf(mlbuf[ww][q][0] - mstar);
        linv[q] = 1.f / ls;
    }
    float (*bufp)[97] = (w & 1) ? obufB : obufA;
    if (w < 2) {
#pragma unroll
        for (int r = 0; r < 16; ++r) {
            const int vr = (r & 3) + 8 * (r >> 2) + 4 * hi;
            bufp[q][vr] = acc0[r] * wme;
            bufp[q][32 + vr] = acc1[r] * wme;
            bufp[q][64 + vr] = acc2[r] * wme;
        }
    }
    __syncthreads();
    if (w >= 2) {
#pragma unroll
        for (int r = 0; r < 16; ++r) {
            const int vr = (r & 3) + 8 * (r >> 2) + 4 * hi;
            bufp[q][vr] += acc0[r] * wme;
            bufp[q][32 + vr] += acc1[r] * wme;
            bufp[q][64 + vr] += acc2[r] * wme;
        }
    }
    __syncthreads();
    // ---- write O (bf16) ----
    const int qo = tid >> 3, v0 = (tid & 7) * 12;
    const float li = linv[qo];
    __bf16* prow = P + ((size_t)b * Tn + t0 + qo) * Dn + h * Vn + v0;
#pragma unroll
    for (int j = 0; j < 12; j += 2) {
        const float u0 = (obufA[qo][v0 + j] + obufB[qo][v0 + j]) * li;
        const float u1 = (obufA[qo][v0 + j + 1] + obufB[qo][v0 + j + 1]) * li;
        union { __bf16 hh[2]; unsigned int u; } pk;
        pk.hh[0] = (__bf16)u0; pk.hh[1] = (__bf16)u1;
        *(unsigned int*)(prow + j) = pk.u;
    }
}

extern "C" void kernel_launch(void* const* d_in, const int* in_sizes, int n_in,
                              void* d_out, int out_size, void* d_ws, size_t ws_size,
                              hipStream_t stream) {
    (void)in_sizes; (void)n_in; (void)out_size; (void)ws_size;
    const float* x   = (const float*)d_in[0];
    const float* Wq  = (const float*)d_in[1];
    const float* Wk  = (const float*)d_in[2];
    const float* Wv  = (const float*)d_in[3];
    const float* Wrk = (const float*)d_in[4];
    const float* rwb = (const float*)d_in[5];
    const float* rrb = (const float*)d_in[6];
    const float* Wo  = (const float*)d_in[7];
    const float* bo  = (const float*)d_in[8];
    float* out = (float*)d_out;

    char* p = (char*)d_ws;
    auto alloc = [&](size_t bytes) { char* r = p; p += (bytes + 255) & ~(size_t)255; return r; };
    float*  Sb   = (float*)alloc((size_t)Bn * Hn * Tn * 35 * 4);
    __bf16* cbb  = (__bf16*)alloc((size_t)Bn * Hn * Tn * 2);
    __bf16* qhb  = (__bf16*)alloc((size_t)Bn * Hn * Tn * Kn * 2);
    __bf16* khb  = (__bf16*)alloc((size_t)Bn * Hn * Tn * Kn * 2);
    __bf16* vtb  = (__bf16*)alloc((size_t)Bn * Hn * 96 * Tn * 2);
    __bf16* Pmb  = (__bf16*)alloc((size_t)Bn * Tn * Dn * 2);
    __bf16* Xb   = (__bf16*)alloc((size_t)Bn * Tn * Dn * 2);
    __bf16* WT   = (__bf16*)alloc((size_t)1792 * 768 * 2);
    __bf16* WoT  = (__bf16*)alloc((size_t)768 * 768 * 2);

    castx_kernel<<<dim3(1536), 256, 0, stream>>>(x, Xb, Bn * Tn * Dn / 4);
    transpose_kernel<<<dim3(16, 24), 256, 0, stream>>>(Wq, WT, 768, 512);
    transpose_kernel<<<dim3(16, 24), 256, 0, stream>>>(Wk, WT + (size_t)512 * 768, 768, 512);
    transpose_kernel<<<dim3(24, 24), 256, 0, stream>>>(Wv, WT + (size_t)1024 * 768, 768, 768);
    transpose_kernel<<<dim3(24, 24), 256, 0, stream>>>(Wo, WoT, 768, 768);
    gemm_kernel<<<dim3(14, 32), 256, 0, stream>>>(Xb, WT, 768, 0, qhb, khb, vtb, nullptr, nullptr);
    bias_kernel<<<dim3(Tn / 32, Bn * Hn), 256, 0, stream>>>(qhb, khb, Wrk, rwb, rrb, Sb, cbb);
    attn_kernel<<<dim3(Tn / 32, Bn * Hn), 256, 0, stream>>>(qhb, khb, vtb, Sb, cbb, Pmb);
    gemm_kernel<<<dim3(6, 32), 256, 0, stream>>>(Pmb, WoT, 768, 1, nullptr, nullptr, nullptr, out, bo);
}